// Round 5
// baseline (547.487 us; speedup 1.0000x reference)
//
#include <hip/hip_runtime.h>
#include <stdint.h>

#define NUM_EXPERT 8
#define IN_FEAT 1024
#define OUT_FEAT 4096
#define N_TOKENS 4096

#define BM 128
#define BN 128
#define BK 64
#define MAX_ROW_TILES 40      // worst-case sum_e ceil(cnt_e/128)

typedef __attribute__((ext_vector_type(8))) short short8;   // 8 x bf16 bits
typedef __attribute__((ext_vector_type(4))) float f32x4;

__device__ __forceinline__ void async_cp16(const void* g, void* l) {
    __builtin_amdgcn_global_load_lds(
        (const __attribute__((address_space(1))) void*)g,
        (__attribute__((address_space(3))) void*)l, 16, 0, 0);
}

__device__ __forceinline__ unsigned int rne2(float a, float b) {
    // pack 2 fp32 -> 2 bf16 (RNE) into one dword (a=low, b=high)
    unsigned int ua = __float_as_uint(a); ua += 0x7fffu + ((ua >> 16) & 1u);
    unsigned int ub = __float_as_uint(b); ub += 0x7fffu + ((ub >> 16) & 1u);
    return (ua >> 16) | (ub & 0xffff0000u);
}

// ---------------- Kernel 0: fp32 -> bf16 convert (memory-bound) --------------
__global__ __launch_bounds__(256)
void cvt_bf16(const float4* __restrict__ src, uint2* __restrict__ dst, int n4) {
    int i = blockIdx.x * 256 + threadIdx.x;
    int stride = gridDim.x * 256;
    for (; i < n4; i += stride) {
        float4 v = src[i];
        uint2 r;
        r.x = rne2(v.x, v.y);
        r.y = rne2(v.z, v.w);
        dst[i] = r;
    }
}

// ---------------- Kernel 1: counting sort of tokens by expert ----------------
// meta layout (int): [0..7]=cnt, [8..15]=off, [16..16+4096)=perm
__global__ __launch_bounds__(256)
void moe_sort(const int* __restrict__ gate, int* __restrict__ meta) {
    __shared__ int cnt[NUM_EXPERT];
    __shared__ int off[NUM_EXPERT];
    __shared__ int wsum[4];
    const int tid  = threadIdx.x;
    const int lane = tid & 63;
    const int wave = tid >> 6;

    int gv[16];
    const int4* gp = (const int4*)(gate + tid * 16);
#pragma unroll
    for (int i = 0; i < 4; ++i) {
        int4 v = gp[i];
        gv[i * 4 + 0] = v.x; gv[i * 4 + 1] = v.y;
        gv[i * 4 + 2] = v.z; gv[i * 4 + 3] = v.w;
    }
    int lc[NUM_EXPERT];
#pragma unroll
    for (int e = 0; e < NUM_EXPERT; ++e) {
        int c = 0;
#pragma unroll
        for (int j = 0; j < 16; ++j) c += (gv[j] == e) ? 1 : 0;
        lc[e] = c;
    }
    if (tid < NUM_EXPERT) cnt[tid] = 0;
    __syncthreads();
#pragma unroll
    for (int e = 0; e < NUM_EXPERT; ++e) {
        int c = lc[e];
#pragma unroll
        for (int d = 32; d > 0; d >>= 1) c += __shfl_down(c, d);
        if (lane == 0 && c) atomicAdd(&cnt[e], c);
    }
    __syncthreads();
    if (tid == 0) {
        int a = 0;
#pragma unroll
        for (int e = 0; e < NUM_EXPERT; ++e) { off[e] = a; a += cnt[e]; }
    }
    __syncthreads();
    if (tid < NUM_EXPERT) { meta[tid] = cnt[tid]; meta[8 + tid] = off[tid]; }

    int* perm = meta + 16;
#pragma unroll
    for (int e = 0; e < NUM_EXPERT; ++e) {
        int c_t = lc[e];
        int inc = c_t;
#pragma unroll
        for (int d = 1; d < 64; d <<= 1) {
            int t = __shfl_up(inc, d);
            if (lane >= d) inc += t;
        }
        if (lane == 63) wsum[wave] = inc;
        __syncthreads();
        int base = off[e];
#pragma unroll
        for (int w = 0; w < 4; ++w) if (w < wave) base += wsum[w];
        int rank = base + inc - c_t;
#pragma unroll
        for (int j = 0; j < 16; ++j) {
            if (gv[j] == e) { perm[rank] = tid * 16 + j; rank++; }
        }
        __syncthreads();
    }
}

// ---------------- Kernel 2: bf16 grouped GEMM, LDS = exactly 32 KB -----------
// C[tok][n] = sum_k inp[tok][k] * W[e][n][k]   (both operands K-contiguous)
__global__ __launch_bounds__(256, 5)   // 5 blocks/CU: all 1280 blocks resident
void moe_gemm_bf16(const unsigned short* __restrict__ inp,
                   const unsigned short* __restrict__ weight,
                   const int* __restrict__ meta,
                   float* __restrict__ out) {
    __shared__ __align__(16) unsigned short As[BM * BK];   // 16 KB
    __shared__ __align__(16) unsigned short Bs[BN * BK];   // 16 KB  (total 32768 B)

    const int* cnt  = meta;
    const int* off  = meta + 8;
    const int* perm = meta + 16;

    // ---- map blockIdx.y -> (expert, local row-tile); block-uniform ----
    int local = blockIdx.y;
    int e = -1, grp_cnt = 0, grp_off = 0;
#pragma unroll
    for (int i = 0; i < NUM_EXPERT; ++i) {
        int c = cnt[i];
        int t = (c + BM - 1) >> 7;
        if (e < 0) {
            if (local < t) { e = i; grp_cnt = c; grp_off = off[i]; }
            else           local -= t;
        }
    }
    if (e < 0) return;

    const int n0   = blockIdx.x * BN;
    const int row0 = local * BM;
    int vcnt = grp_cnt - row0; if (vcnt > BM) vcnt = BM;

    const int tid  = threadIdx.x;
    const int lane = tid & 63;
    const int wave = tid >> 6;

    // ---- staging descriptors: thread stages chunks c = i*256+tid (16 B each).
    // LDS slot (row=c>>3, kcp=c&7) receives global chunk kc = kcp ^ (row&7).
    const char* ag[4]; const char* bg[4];
    char* al[4]; char* bl[4];
    const char* inp_b = (const char*)inp;
    const char* w_b   = (const char*)weight + (size_t)e * (size_t)(OUT_FEAT * IN_FEAT) * 2;
#pragma unroll
    for (int i = 0; i < 4; ++i) {
        int c   = i * 256 + tid;
        int row = c >> 3;
        int kc  = (c & 7) ^ (row & 7);
        int p   = row0 + row; if (p > grp_cnt - 1) p = grp_cnt - 1;  // clamp tail
        int tok = perm[grp_off + p];
        ag[i] = inp_b + (size_t)tok * (IN_FEAT * 2) + kc * 16;
        bg[i] = w_b   + (size_t)(n0 + row) * (IN_FEAT * 2) + kc * 16;
        al[i] = (char*)As + c * 16;
        bl[i] = (char*)Bs + c * 16;
    }

    // ---- fragment LDS byte offsets: row*128 + ((ks*4+quad)^(row&7))*16 ----
    const int wm   = (wave & 1) * 64;
    const int wn   = (wave >> 1) * 64;
    const int lcol = lane & 15;
    const int quad = lane >> 4;

    int aoff[2][4], boff[2][4];
#pragma unroll
    for (int ks = 0; ks < 2; ++ks)
#pragma unroll
        for (int t = 0; t < 4; ++t) {
            int ra = wm + t * 16 + lcol;
            aoff[ks][t] = ra * 128 + (((ks * 4 + quad) ^ (ra & 7)) * 16);
            int rb = wn + t * 16 + lcol;
            boff[ks][t] = rb * 128 + (((ks * 4 + quad) ^ (rb & 7)) * 16);
        }

    const f32x4 vzero = {0.f, 0.f, 0.f, 0.f};
    f32x4 acc[4][4];
#pragma unroll
    for (int i = 0; i < 4; ++i)
#pragma unroll
        for (int j = 0; j < 4; ++j) acc[i][j] = vzero;

    const char* As_b = (const char*)As;
    const char* Bs_b = (const char*)Bs;

    for (int k0 = 0; k0 < IN_FEAT; k0 += BK) {
#pragma unroll
        for (int i = 0; i < 4; ++i) { async_cp16(ag[i], al[i]); ag[i] += BK * 2; }
#pragma unroll
        for (int i = 0; i < 4; ++i) { async_cp16(bg[i], bl[i]); bg[i] += BK * 2; }
        __builtin_amdgcn_s_waitcnt(0);   // drain global_load_lds before barrier
        __syncthreads();
#pragma unroll
        for (int ks = 0; ks < 2; ++ks) {
            short8 af[4], bf[4];
#pragma unroll
            for (int im = 0; im < 4; ++im) af[im] = *(const short8*)(As_b + aoff[ks][im]);
#pragma unroll
            for (int jn = 0; jn < 4; ++jn) bf[jn] = *(const short8*)(Bs_b + boff[ks][jn]);
#pragma unroll
            for (int im = 0; im < 4; ++im)
#pragma unroll
                for (int jn = 0; jn < 4; ++jn)
                    acc[im][jn] = __builtin_amdgcn_mfma_f32_16x16x32_bf16(
                        af[im], bf[jn], acc[im][jn], 0, 0, 0);
        }
        __syncthreads();
    }

    // ---- epilogue: C/D layout col=lane&15, row=quad*4+reg; fp32 scatter ----
#pragma unroll
    for (int im = 0; im < 4; ++im) {
#pragma unroll
        for (int reg = 0; reg < 4; ++reg) {
            int r = wm + im * 16 + quad * 4 + reg;
            if (r < vcnt) {
                int tok = perm[grp_off + row0 + r];
                float* orow = out + (size_t)tok * OUT_FEAT + (n0 + wn + lcol);
#pragma unroll
                for (int jn = 0; jn < 4; ++jn)
                    orow[jn * 16] = acc[im][jn][reg];
            }
        }
    }
}

extern "C" void kernel_launch(void* const* d_in, const int* in_sizes, int n_in,
                              void* d_out, int out_size, void* d_ws, size_t ws_size,
                              hipStream_t stream) {
    const float* inp    = (const float*)d_in[0];   // fp32 [4096,1024]
    const int*   gate   = (const int*)d_in[1];     // int32 [4096]
    const float* weight = (const float*)d_in[2];   // fp32 [8,4096,1024]
    float*       out    = (float*)d_out;           // fp32 [4096,4096]
    (void)in_sizes; (void)n_in; (void)out_size; (void)ws_size;

    const size_t n_inp = (size_t)N_TOKENS * IN_FEAT;                 // 4M elems
    const size_t n_w   = (size_t)NUM_EXPERT * OUT_FEAT * IN_FEAT;    // 32M elems

    unsigned short* wsA  = (unsigned short*)d_ws;        // 8 MB bf16 inp
    unsigned short* wsB  = wsA + n_inp;                  // 64 MB bf16 weight
    int*            meta = (int*)(wsB + n_w);            // cnt/off/perm (~16.5 KB)

    moe_sort<<<1, 256, 0, stream>>>(gate, meta);
    cvt_bf16<<<512,  256, 0, stream>>>((const float4*)inp,    (uint2*)wsA, (int)(n_inp / 4));
    cvt_bf16<<<2048, 256, 0, stream>>>((const float4*)weight, (uint2*)wsB, (int)(n_w / 4));
    dim3 grid(OUT_FEAT / BN, MAX_ROW_TILES);
    moe_gemm_bf16<<<grid, 256, 0, stream>>>(wsA, wsB, meta, out);
}

// Round 6
// 292.137 us; speedup vs baseline: 1.8741x; 1.8741x over previous
//
#include <hip/hip_runtime.h>
#include <stdint.h>

#define NUM_EXPERT 8
#define IN_FEAT 1024
#define OUT_FEAT 4096
#define N_TOKENS 4096

#define BM 128
#define BN 128
#define BK 64
#define MAX_ROW_TILES 40      // worst-case sum_e ceil(cnt_e/128)

typedef __attribute__((ext_vector_type(8))) short short8;   // 8 x bf16 bits
typedef __attribute__((ext_vector_type(4))) float f32x4;

__device__ __forceinline__ void async_cp16(const void* g, void* l) {
    __builtin_amdgcn_global_load_lds(
        (const __attribute__((address_space(1))) void*)g,
        (__attribute__((address_space(3))) void*)l, 16, 0, 0);
}

__device__ __forceinline__ unsigned int rne2(float a, float b) {
    // pack 2 fp32 -> 2 bf16 (RNE) into one dword (a=low, b=high)
    unsigned int ua = __float_as_uint(a); ua += 0x7fffu + ((ua >> 16) & 1u);
    unsigned int ub = __float_as_uint(b); ub += 0x7fffu + ((ub >> 16) & 1u);
    return (ua >> 16) | (ub & 0xffff0000u);
}

// ---------------- Kernel 0: fp32 -> bf16 convert (memory-bound) --------------
__global__ __launch_bounds__(256)
void cvt_bf16(const float4* __restrict__ src, uint2* __restrict__ dst, int n4) {
    int i = blockIdx.x * 256 + threadIdx.x;
    int stride = gridDim.x * 256;
    for (; i < n4; i += stride) {
        float4 v = src[i];
        uint2 r;
        r.x = rne2(v.x, v.y);
        r.y = rne2(v.z, v.w);
        dst[i] = r;
    }
}

// ---------------- Kernel 1: counting sort of tokens by expert ----------------
// meta layout (int): [0..7]=cnt, [8..15]=off, [16..16+4096)=perm
__global__ __launch_bounds__(256)
void moe_sort(const int* __restrict__ gate, int* __restrict__ meta) {
    __shared__ int cnt[NUM_EXPERT];
    __shared__ int off[NUM_EXPERT];
    __shared__ int wsum[4];
    const int tid  = threadIdx.x;
    const int lane = tid & 63;
    const int wave = tid >> 6;

    int gv[16];
    const int4* gp = (const int4*)(gate + tid * 16);
#pragma unroll
    for (int i = 0; i < 4; ++i) {
        int4 v = gp[i];
        gv[i * 4 + 0] = v.x; gv[i * 4 + 1] = v.y;
        gv[i * 4 + 2] = v.z; gv[i * 4 + 3] = v.w;
    }
    int lc[NUM_EXPERT];
#pragma unroll
    for (int e = 0; e < NUM_EXPERT; ++e) {
        int c = 0;
#pragma unroll
        for (int j = 0; j < 16; ++j) c += (gv[j] == e) ? 1 : 0;
        lc[e] = c;
    }
    if (tid < NUM_EXPERT) cnt[tid] = 0;
    __syncthreads();
#pragma unroll
    for (int e = 0; e < NUM_EXPERT; ++e) {
        int c = lc[e];
#pragma unroll
        for (int d = 32; d > 0; d >>= 1) c += __shfl_down(c, d);
        if (lane == 0 && c) atomicAdd(&cnt[e], c);
    }
    __syncthreads();
    if (tid == 0) {
        int a = 0;
#pragma unroll
        for (int e = 0; e < NUM_EXPERT; ++e) { off[e] = a; a += cnt[e]; }
    }
    __syncthreads();
    if (tid < NUM_EXPERT) { meta[tid] = cnt[tid]; meta[8 + tid] = off[tid]; }

    int* perm = meta + 16;
#pragma unroll
    for (int e = 0; e < NUM_EXPERT; ++e) {
        int c_t = lc[e];
        int inc = c_t;
#pragma unroll
        for (int d = 1; d < 64; d <<= 1) {
            int t = __shfl_up(inc, d);
            if (lane >= d) inc += t;
        }
        if (lane == 63) wsum[wave] = inc;
        __syncthreads();
        int base = off[e];
#pragma unroll
        for (int w = 0; w < 4; ++w) if (w < wave) base += wsum[w];
        int rank = base + inc - c_t;
#pragma unroll
        for (int j = 0; j < 16; ++j) {
            if (gv[j] == e) { perm[rank] = tid * 16 + j; rank++; }
        }
        __syncthreads();
    }
}

// ---------------- Kernel 2: bf16 grouped GEMM, LDS = exactly 32 KB -----------
// C[tok][n] = sum_k inp[tok][k] * W[e][n][k]   (both operands K-contiguous)
// NOTE: plain __launch_bounds__(256). The (256,5) min-waves hint forced VGPR
// down to 48 and spilled the 64-VGPR accumulator to scratch (WRITE_SIZE 65MB
// -> 478MB, 3.5x slower). With natural VGPR (~92) and LDS=32768, HW gives
// floor(512/96)=5 waves/SIMD = 5 blocks/CU on its own.
__global__ __launch_bounds__(256)
void moe_gemm_bf16(const unsigned short* __restrict__ inp,
                   const unsigned short* __restrict__ weight,
                   const int* __restrict__ meta,
                   float* __restrict__ out) {
    __shared__ __align__(16) unsigned short As[BM * BK];   // 16 KB
    __shared__ __align__(16) unsigned short Bs[BN * BK];   // 16 KB  (total 32768 B)

    const int* cnt  = meta;
    const int* off  = meta + 8;
    const int* perm = meta + 16;

    // ---- map blockIdx.y -> (expert, local row-tile); block-uniform ----
    int local = blockIdx.y;
    int e = -1, grp_cnt = 0, grp_off = 0;
#pragma unroll
    for (int i = 0; i < NUM_EXPERT; ++i) {
        int c = cnt[i];
        int t = (c + BM - 1) >> 7;
        if (e < 0) {
            if (local < t) { e = i; grp_cnt = c; grp_off = off[i]; }
            else           local -= t;
        }
    }
    if (e < 0) return;

    const int n0   = blockIdx.x * BN;
    const int row0 = local * BM;
    int vcnt = grp_cnt - row0; if (vcnt > BM) vcnt = BM;

    const int tid  = threadIdx.x;
    const int lane = tid & 63;
    const int wave = tid >> 6;

    // ---- staging descriptors: thread stages chunks c = i*256+tid (16 B each).
    // LDS slot (row=c>>3, kcp=c&7) receives global chunk kc = kcp ^ (row&7).
    const char* ag[4]; const char* bg[4];
    char* al[4]; char* bl[4];
    const char* inp_b = (const char*)inp;
    const char* w_b   = (const char*)weight + (size_t)e * (size_t)(OUT_FEAT * IN_FEAT) * 2;
#pragma unroll
    for (int i = 0; i < 4; ++i) {
        int c   = i * 256 + tid;
        int row = c >> 3;
        int kc  = (c & 7) ^ (row & 7);
        int p   = row0 + row; if (p > grp_cnt - 1) p = grp_cnt - 1;  // clamp tail
        int tok = perm[grp_off + p];
        ag[i] = inp_b + (size_t)tok * (IN_FEAT * 2) + kc * 16;
        bg[i] = w_b   + (size_t)(n0 + row) * (IN_FEAT * 2) + kc * 16;
        al[i] = (char*)As + c * 16;
        bl[i] = (char*)Bs + c * 16;
    }

    // ---- fragment LDS byte offsets: row*128 + ((ks*4+quad)^(row&7))*16 ----
    const int wm   = (wave & 1) * 64;
    const int wn   = (wave >> 1) * 64;
    const int lcol = lane & 15;
    const int quad = lane >> 4;

    int aoff[2][4], boff[2][4];
#pragma unroll
    for (int ks = 0; ks < 2; ++ks)
#pragma unroll
        for (int t = 0; t < 4; ++t) {
            int ra = wm + t * 16 + lcol;
            aoff[ks][t] = ra * 128 + (((ks * 4 + quad) ^ (ra & 7)) * 16);
            int rb = wn + t * 16 + lcol;
            boff[ks][t] = rb * 128 + (((ks * 4 + quad) ^ (rb & 7)) * 16);
        }

    const f32x4 vzero = {0.f, 0.f, 0.f, 0.f};
    f32x4 acc[4][4];
#pragma unroll
    for (int i = 0; i < 4; ++i)
#pragma unroll
        for (int j = 0; j < 4; ++j) acc[i][j] = vzero;

    const char* As_b = (const char*)As;
    const char* Bs_b = (const char*)Bs;

    for (int k0 = 0; k0 < IN_FEAT; k0 += BK) {
#pragma unroll
        for (int i = 0; i < 4; ++i) { async_cp16(ag[i], al[i]); ag[i] += BK * 2; }
#pragma unroll
        for (int i = 0; i < 4; ++i) { async_cp16(bg[i], bl[i]); bg[i] += BK * 2; }
        __builtin_amdgcn_s_waitcnt(0);   // drain global_load_lds before barrier
        __syncthreads();
#pragma unroll
        for (int ks = 0; ks < 2; ++ks) {
            short8 af[4], bf[4];
#pragma unroll
            for (int im = 0; im < 4; ++im) af[im] = *(const short8*)(As_b + aoff[ks][im]);
#pragma unroll
            for (int jn = 0; jn < 4; ++jn) bf[jn] = *(const short8*)(Bs_b + boff[ks][jn]);
#pragma unroll
            for (int im = 0; im < 4; ++im)
#pragma unroll
                for (int jn = 0; jn < 4; ++jn)
                    acc[im][jn] = __builtin_amdgcn_mfma_f32_16x16x32_bf16(
                        af[im], bf[jn], acc[im][jn], 0, 0, 0);
        }
        __syncthreads();
    }

    // ---- epilogue: C/D layout col=lane&15, row=quad*4+reg; fp32 scatter ----
#pragma unroll
    for (int im = 0; im < 4; ++im) {
#pragma unroll
        for (int reg = 0; reg < 4; ++reg) {
            int r = wm + im * 16 + quad * 4 + reg;
            if (r < vcnt) {
                int tok = perm[grp_off + row0 + r];
                float* orow = out + (size_t)tok * OUT_FEAT + (n0 + wn + lcol);
#pragma unroll
                for (int jn = 0; jn < 4; ++jn)
                    orow[jn * 16] = acc[im][jn][reg];
            }
        }
    }
}

extern "C" void kernel_launch(void* const* d_in, const int* in_sizes, int n_in,
                              void* d_out, int out_size, void* d_ws, size_t ws_size,
                              hipStream_t stream) {
    const float* inp    = (const float*)d_in[0];   // fp32 [4096,1024]
    const int*   gate   = (const int*)d_in[1];     // int32 [4096]
    const float* weight = (const float*)d_in[2];   // fp32 [8,4096,1024]
    float*       out    = (float*)d_out;           // fp32 [4096,4096]
    (void)in_sizes; (void)n_in; (void)out_size; (void)ws_size;

    const size_t n_inp = (size_t)N_TOKENS * IN_FEAT;                 // 4M elems
    const size_t n_w   = (size_t)NUM_EXPERT * OUT_FEAT * IN_FEAT;    // 32M elems

    unsigned short* wsA  = (unsigned short*)d_ws;        // 8 MB bf16 inp
    unsigned short* wsB  = wsA + n_inp;                  // 64 MB bf16 weight
    int*            meta = (int*)(wsB + n_w);            // cnt/off/perm (~16.5 KB)

    moe_sort<<<1, 256, 0, stream>>>(gate, meta);
    cvt_bf16<<<512,  256, 0, stream>>>((const float4*)inp,    (uint2*)wsA, (int)(n_inp / 4));
    cvt_bf16<<<2048, 256, 0, stream>>>((const float4*)weight, (uint2*)wsB, (int)(n_w / 4));
    dim3 grid(OUT_FEAT / BN, MAX_ROW_TILES);
    moe_gemm_bf16<<<grid, 256, 0, stream>>>(wsA, wsB, meta, out);
}

// Round 8
// 281.184 us; speedup vs baseline: 1.9471x; 1.0390x over previous
//
#include <hip/hip_runtime.h>
#include <stdint.h>

#define NUM_EXPERT 8
#define IN_FEAT 1024
#define OUT_FEAT 4096
#define N_TOKENS 4096

#define BM 128
#define BN 128
#define BK 64
#define MAX_ROW_TILES 40      // worst-case sum_e ceil(cnt_e/128)
#define PREP_BLKS 2080        // last block sorts; 2079 blocks convert

typedef __attribute__((ext_vector_type(8))) short short8;   // 8 x bf16 bits
typedef __attribute__((ext_vector_type(4))) float f32x4;

__device__ __forceinline__ void async_cp16(const void* g, void* l) {
    __builtin_amdgcn_global_load_lds(
        (const __attribute__((address_space(1))) void*)g,
        (__attribute__((address_space(3))) void*)l, 16, 0, 0);
}

__device__ __forceinline__ unsigned int rne2(float a, float b) {
    // pack 2 fp32 -> 2 bf16 (RNE) into one dword (a=low, b=high)
    unsigned int ua = __float_as_uint(a); ua += 0x7fffu + ((ua >> 16) & 1u);
    unsigned int ub = __float_as_uint(b); ub += 0x7fffu + ((ub >> 16) & 1u);
    return (ua >> 16) | (ub & 0xffff0000u);
}

// ---------------- Kernel 1: prep = sort (last block) + fp32->bf16 cvt --------
// meta layout (int): [0..7]=cnt, [8..15]=off, [16..16+4096)=perm
// No grid sync needed: the GEMM is a separate stream-ordered launch.
__global__ __launch_bounds__(256)
void moe_prep(const float* __restrict__ inp_f,
              const int* __restrict__ gate,
              const float* __restrict__ weight_f,
              unsigned short* __restrict__ wsA,
              unsigned short* __restrict__ wsB,
              int* __restrict__ meta) {
    const int tid = threadIdx.x;
    const int bid = blockIdx.x;

    if (bid == PREP_BLKS - 1) {
        // ---------------- sort: one block, validated logic ----------------
        __shared__ int cnt[NUM_EXPERT];
        __shared__ int off[NUM_EXPERT];
        __shared__ int wsum[4];
        const int lane = tid & 63;
        const int wave = tid >> 6;

        int gv[16];
        const int4* gp = (const int4*)(gate + tid * 16);
#pragma unroll
        for (int i = 0; i < 4; ++i) {
            int4 v = gp[i];
            gv[i * 4 + 0] = v.x; gv[i * 4 + 1] = v.y;
            gv[i * 4 + 2] = v.z; gv[i * 4 + 3] = v.w;
        }
        int lc[NUM_EXPERT];
#pragma unroll
        for (int e = 0; e < NUM_EXPERT; ++e) {
            int c = 0;
#pragma unroll
            for (int j = 0; j < 16; ++j) c += (gv[j] == e) ? 1 : 0;
            lc[e] = c;
        }
        if (tid < NUM_EXPERT) cnt[tid] = 0;
        __syncthreads();
#pragma unroll
        for (int e = 0; e < NUM_EXPERT; ++e) {
            int c = lc[e];
#pragma unroll
            for (int d = 32; d > 0; d >>= 1) c += __shfl_down(c, d);
            if (lane == 0 && c) atomicAdd(&cnt[e], c);
        }
        __syncthreads();
        if (tid == 0) {
            int a = 0;
#pragma unroll
            for (int e = 0; e < NUM_EXPERT; ++e) { off[e] = a; a += cnt[e]; }
        }
        __syncthreads();
        if (tid < NUM_EXPERT) { meta[tid] = cnt[tid]; meta[8 + tid] = off[tid]; }

        int* perm = meta + 16;
#pragma unroll
        for (int e = 0; e < NUM_EXPERT; ++e) {
            int c_t = lc[e];
            int inc = c_t;
#pragma unroll
            for (int d = 1; d < 64; d <<= 1) {
                int t = __shfl_up(inc, d);
                if (lane >= d) inc += t;
            }
            if (lane == 63) wsum[wave] = inc;
            __syncthreads();
            int base = off[e];
#pragma unroll
            for (int w = 0; w < 4; ++w) if (w < wave) base += wsum[w];
            int rank = base + inc - c_t;
#pragma unroll
            for (int j = 0; j < 16; ++j) {
                if (gv[j] == e) { perm[rank] = tid * 16 + j; rank++; }
            }
            __syncthreads();
        }
    } else {
        // ---------------- convert: grid-stride over inp then weight --------
        const int n4_inp = (N_TOKENS * IN_FEAT) / 4;                       // 1M
        const int n4_tot = n4_inp + (NUM_EXPERT * OUT_FEAT * IN_FEAT) / 4; // 9M
        int i = bid * 256 + tid;
        const int stride = (PREP_BLKS - 1) * 256;
        for (; i < n4_tot; i += stride) {
            const float4* src; uint2* dst; int idx;
            if (i < n4_inp) { src = (const float4*)inp_f;    dst = (uint2*)wsA; idx = i; }
            else            { src = (const float4*)weight_f; dst = (uint2*)wsB; idx = i - n4_inp; }
            float4 v = src[idx];
            uint2 r;
            r.x = rne2(v.x, v.y);
            r.y = rne2(v.z, v.w);
            dst[idx] = r;
        }
    }
}

// ---------------- Kernel 2: bf16 grouped GEMM, LDS = exactly 32 KB -----------
// C[tok][n] = sum_k inp[tok][k] * W[e][n][k]   (both operands K-contiguous)
// NOTE: plain __launch_bounds__(256). A (256,5) min-waves hint forced VGPR
// 92->48 and spilled the accumulator to scratch (3.5x slower, R5). With
// natural VGPR (~92) and LDS=32768, HW gives 5 waves/SIMD on its own.
__global__ __launch_bounds__(256)
void moe_gemm_bf16(const unsigned short* __restrict__ inp,
                   const unsigned short* __restrict__ weight,
                   const int* __restrict__ meta,
                   float* __restrict__ out) {
    __shared__ __align__(16) unsigned short As[BM * BK];   // 16 KB
    __shared__ __align__(16) unsigned short Bs[BN * BK];   // 16 KB  (total 32768 B)

    const int* cnt  = meta;
    const int* off  = meta + 8;
    const int* perm = meta + 16;

    // ---- map blockIdx.y -> (expert, local row-tile); block-uniform ----
    int local = blockIdx.y;
    int e = -1, grp_cnt = 0, grp_off = 0;
#pragma unroll
    for (int i = 0; i < NUM_EXPERT; ++i) {
        int c = cnt[i];
        int t = (c + BM - 1) >> 7;
        if (e < 0) {
            if (local < t) { e = i; grp_cnt = c; grp_off = off[i]; }
            else           local -= t;
        }
    }
    if (e < 0) return;

    const int n0   = blockIdx.x * BN;
    const int row0 = local * BM;
    int vcnt = grp_cnt - row0; if (vcnt > BM) vcnt = BM;

    const int tid  = threadIdx.x;
    const int lane = tid & 63;
    const int wave = tid >> 6;

    // ---- staging descriptors: thread stages chunks c = i*256+tid (16 B each).
    // LDS slot (row=c>>3, kcp=c&7) receives global chunk kc = kcp ^ (row&7).
    const char* ag[4]; const char* bg[4];
    char* al[4]; char* bl[4];
    const char* inp_b = (const char*)inp;
    const char* w_b   = (const char*)weight + (size_t)e * (size_t)(OUT_FEAT * IN_FEAT) * 2;
#pragma unroll
    for (int i = 0; i < 4; ++i) {
        int c   = i * 256 + tid;
        int row = c >> 3;
        int kc  = (c & 7) ^ (row & 7);
        int p   = row0 + row; if (p > grp_cnt - 1) p = grp_cnt - 1;  // clamp tail
        int tok = perm[grp_off + p];
        ag[i] = inp_b + (size_t)tok * (IN_FEAT * 2) + kc * 16;
        bg[i] = w_b   + (size_t)(n0 + row) * (IN_FEAT * 2) + kc * 16;
        al[i] = (char*)As + c * 16;
        bl[i] = (char*)Bs + c * 16;
    }

    // ---- fragment LDS byte offsets: row*128 + ((ks*4+quad)^(row&7))*16 ----
    const int wm   = (wave & 1) * 64;
    const int wn   = (wave >> 1) * 64;
    const int lcol = lane & 15;
    const int quad = lane >> 4;

    int aoff[2][4], boff[2][4];
#pragma unroll
    for (int ks = 0; ks < 2; ++ks)
#pragma unroll
        for (int t = 0; t < 4; ++t) {
            int ra = wm + t * 16 + lcol;
            aoff[ks][t] = ra * 128 + (((ks * 4 + quad) ^ (ra & 7)) * 16);
            int rb = wn + t * 16 + lcol;
            boff[ks][t] = rb * 128 + (((ks * 4 + quad) ^ (rb & 7)) * 16);
        }

    const f32x4 vzero = {0.f, 0.f, 0.f, 0.f};
    f32x4 acc[4][4];
#pragma unroll
    for (int i = 0; i < 4; ++i)
#pragma unroll
        for (int j = 0; j < 4; ++j) acc[i][j] = vzero;

    const char* As_b = (const char*)As;
    const char* Bs_b = (const char*)Bs;

    for (int k0 = 0; k0 < IN_FEAT; k0 += BK) {
#pragma unroll
        for (int i = 0; i < 4; ++i) { async_cp16(ag[i], al[i]); ag[i] += BK * 2; }
#pragma unroll
        for (int i = 0; i < 4; ++i) { async_cp16(bg[i], bl[i]); bg[i] += BK * 2; }
        __builtin_amdgcn_s_waitcnt(0);   // drain global_load_lds before barrier
        __syncthreads();
#pragma unroll
        for (int ks = 0; ks < 2; ++ks) {
            short8 af[4], bf[4];
#pragma unroll
            for (int im = 0; im < 4; ++im) af[im] = *(const short8*)(As_b + aoff[ks][im]);
#pragma unroll
            for (int jn = 0; jn < 4; ++jn) bf[jn] = *(const short8*)(Bs_b + boff[ks][jn]);
#pragma unroll
            for (int im = 0; im < 4; ++im)
#pragma unroll
                for (int jn = 0; jn < 4; ++jn)
                    acc[im][jn] = __builtin_amdgcn_mfma_f32_16x16x32_bf16(
                        af[im], bf[jn], acc[im][jn], 0, 0, 0);
        }
        __syncthreads();
    }

    // ---- epilogue: C/D layout col=lane&15, row=quad*4+reg; fp32 scatter ----
#pragma unroll
    for (int im = 0; im < 4; ++im) {
#pragma unroll
        for (int reg = 0; reg < 4; ++reg) {
            int r = wm + im * 16 + quad * 4 + reg;
            if (r < vcnt) {
                int tok = perm[grp_off + row0 + r];
                float* orow = out + (size_t)tok * OUT_FEAT + (n0 + wn + lcol);
#pragma unroll
                for (int jn = 0; jn < 4; ++jn)
                    orow[jn * 16] = acc[im][jn][reg];
            }
        }
    }
}

extern "C" void kernel_launch(void* const* d_in, const int* in_sizes, int n_in,
                              void* d_out, int out_size, void* d_ws, size_t ws_size,
                              hipStream_t stream) {
    const float* inp    = (const float*)d_in[0];   // fp32 [4096,1024]
    const int*   gate   = (const int*)d_in[1];     // int32 [4096]
    const float* weight = (const float*)d_in[2];   // fp32 [8,4096,1024]
    float*       out    = (float*)d_out;           // fp32 [4096,4096]
    (void)in_sizes; (void)n_in; (void)out_size; (void)ws_size;

    const size_t n_inp = (size_t)N_TOKENS * IN_FEAT;                 // 4M elems
    const size_t n_w   = (size_t)NUM_EXPERT * OUT_FEAT * IN_FEAT;    // 32M elems

    unsigned short* wsA  = (unsigned short*)d_ws;        // 8 MB bf16 inp
    unsigned short* wsB  = wsA + n_inp;                  // 64 MB bf16 weight
    int*            meta = (int*)(wsB + n_w);            // cnt/off/perm (~16.5 KB)

    moe_prep<<<PREP_BLKS, 256, 0, stream>>>(inp, gate, weight, wsA, wsB, meta);
    dim3 grid(OUT_FEAT / BN, MAX_ROW_TILES);
    moe_gemm_bf16<<<grid, 256, 0, stream>>>(wsA, wsB, meta, out);
}